// Round 9
// baseline (398.562 us; speedup 1.0000x reference)
//
#include <hip/hip_runtime.h>
#include <math.h>

// EuclideanCodebook: x (8,4096,256) fp32, embed (8192,256) fp32
// out = embed[argmin_k ||x - e_k||^2], first-index tie rule.
//
// R14: 256-thread workgroups. Session register-budget law (R6-R13 ledger):
// VGPR cap = 65536/threads, immovable by waves_per_eu (1024->64, 512->128).
// Prediction: 256 thr -> 256-reg cap, which finally fits the low-duplication
// decomposition R12 proved (conflicts halved) but couldn't collect (spilled
// at the 128 cap). Block = 4 waves, owns 64 rows; wave = 64 rows x 16 cols
// (1 rowg x 4 colg): af[4][8]=128 regs, read duplication = 1 (each staged
// byte ds_read ONCE; R11 was 4x, R12 2x) -> 64 b128 per 128 output rows,
// conflicts ~quarter of R11. LDS = 64 KB exactly (2x32KB dbuf, post-loop
// overlays inside) -> best shot yet at 2 blocks/CU (2x256 regs = full SIMD
// file, 128 KB LDS). Sync = R12's validated 1-phase-slack counted scheme:
// wait vmcnt(0) (prev packet, issued 1 full tile earlier) + raw s_barrier,
// THEN issue next packet into the other buffer (WAR-safe: its readers
// lgkm-drained before the barrier), then compute. Grid 512 x 256.
// Selection: 64 streams x top-2 = 128 cands/row (stride-129 merge,
// conflict-free) -> top-4 -> exact fp32 recheck (validated rounding
// sequence, absmax 0 through R13) -> gather.
// Decisive counters: VGPR ~192-224 & WRITE ~58MB = law holds; VGPR=128 =
// law dead -> revert to R11 shell.

#define DIM 256
#define KCODES 8192
#define NROWS 32768
#define TILE_CODES 64
#define NT (KCODES / TILE_CODES)   // 128
#define ROWS_PER_BLK 64

typedef _Float16 half8 __attribute__((ext_vector_type(8)));
typedef _Float16 half4_t __attribute__((ext_vector_type(4)));
typedef float f32x4 __attribute__((ext_vector_type(4)));

// ---- ws layout (bytes) ----
#define ES_OFF 0u                 // 8192*256 f16 = 4194304
#define ESQ_OFF 4194304u          // 8192 f32     = 32768
#define WS_NEED 4227072u

#define GLOAD_LDS16(gp, lp) \
    __builtin_amdgcn_global_load_lds((const __attribute__((address_space(1))) void*)(gp), \
                                     (__attribute__((address_space(3))) void*)(lp), 16, 0, 0)

// ---------------- prep: embed fp32 -> fp16 + e_sq (approx use only) ----------------
__global__ void cvt_esq(const float* __restrict__ emb, _Float16* __restrict__ Es,
                        float* __restrict__ esq) {
    const int gid = blockIdx.x * 256 + threadIdx.x;
    const int code = gid >> 2, q = gid & 3;
    const float4* src = (const float4*)(emb + (size_t)code * DIM + q * 64);
    half4_t* dst = (half4_t*)(Es + (size_t)code * DIM + q * 64);
    float s = 0.f;
#pragma unroll
    for (int i = 0; i < 16; ++i) {
        const float4 v = src[i];
        half4_t h;
        h[0] = (_Float16)v.x; h[1] = (_Float16)v.y; h[2] = (_Float16)v.z; h[3] = (_Float16)v.w;
        dst[i] = h;
        s = fmaf(v.x, v.x, s); s = fmaf(v.y, v.y, s);
        s = fmaf(v.z, v.z, s); s = fmaf(v.w, v.w, s);
    }
    s += __shfl_xor(s, 1);
    s += __shfl_xor(s, 2);
    if (q == 0) esq[code] = s;
}

// ---------------- fused: MFMA score + top-4 + exact recheck + gather ----------------
// grid 512 blocks x 256 threads (4 waves). Block owns rows [blockIdx*64, +64).
// Wave wv = colg (16-col slice of each 64-code tile); every wave covers all 64 rows.
__global__ __attribute__((amdgpu_flat_work_group_size(256, 256))) void vq_fused(
    const float* __restrict__ x, const _Float16* __restrict__ Es,
    const float* __restrict__ esq, const float* __restrict__ embed,
    float* __restrict__ out)
{
    __shared__ __align__(16) char arena[65536];   // 2 x 32 KB tile buffers + overlays

    const int tid = threadIdx.x;    // 0..255
    const int lane = tid & 63;
    const int wv = tid >> 6;        // 0..3
    const int colg = wv;            // 4 col groups x 16 cols
    const int lm = lane & 15;
    const int quad = lane >> 4;
    const int rowblk = blockIdx.x * ROWS_PER_BLK;

    // post-K-loop overlays (all uses after the post-loop __syncthreads)
    float* mb = (float*)arena;                          // [64][129] f = 33024 B
    float (*top4s)[4] = (float (*)[4])(arena + 33792);  // 1024 B
    float (*rd)[4] = (float (*)[4])(arena + 34816);     // 1024 B
    int (*rk)[4] = (int (*)[4])(arena + 35840);         // 1024 B
    int* win = (int*)(arena + 36864);                   // 256 B

    // staging role: wave stages codes [wv*16, wv*16+16) of each tile (8 x 1KB loads)
    const int bpos = lane & 31;
    const _Float16* gp0; const _Float16* gp1; const _Float16* gp2; const _Float16* gp3;
    const _Float16* gp4; const _Float16* gp5; const _Float16* gp6; const _Float16* gp7;
    {
        const int hb = lane >> 5;   // 0/1: which of the two codes in this 1KB load
#define GPINIT(J) (Es + (size_t)(wv * 16 + 2 * (J) + hb) * 256 + \
                   (size_t)((bpos ^ ((wv * 16 + 2 * (J) + hb) & 7)) * 8))
        gp0 = GPINIT(0); gp1 = GPINIT(1); gp2 = GPINIT(2); gp3 = GPINIT(3);
        gp4 = GPINIT(4); gp5 = GPINIT(5); gp6 = GPINIT(6); gp7 = GPINIT(7);
#undef GPINIT
    }

    float e0, e1;

    // packet = one tile: 8 global_load_lds (1 KB each) + 1 esq vector load
#define ISSUE_PKT(TT, BUF, EW) do {                                          \
        char* dst_ = arena + (BUF) * 32768;                                  \
        GLOAD_LDS16(gp0, dst_ + (wv * 16 + 0) * 512);                        \
        GLOAD_LDS16(gp1, dst_ + (wv * 16 + 2) * 512);                        \
        GLOAD_LDS16(gp2, dst_ + (wv * 16 + 4) * 512);                        \
        GLOAD_LDS16(gp3, dst_ + (wv * 16 + 6) * 512);                        \
        GLOAD_LDS16(gp4, dst_ + (wv * 16 + 8) * 512);                        \
        GLOAD_LDS16(gp5, dst_ + (wv * 16 + 10) * 512);                       \
        GLOAD_LDS16(gp6, dst_ + (wv * 16 + 12) * 512);                       \
        GLOAD_LDS16(gp7, dst_ + (wv * 16 + 14) * 512);                       \
        gp0 += TILE_CODES * 256; gp1 += TILE_CODES * 256;                    \
        gp2 += TILE_CODES * 256; gp3 += TILE_CODES * 256;                    \
        gp4 += TILE_CODES * 256; gp5 += TILE_CODES * 256;                    \
        gp6 += TILE_CODES * 256; gp7 += TILE_CODES * 256;                    \
        EW = esq[(size_t)(TT) * TILE_CODES + colg * 16 + lm];                \
    } while (0)

    // one tile: 8 ds_read_b128 (one per ks), 4 MFMA each; 16-slot top-2 epilogue
#define COMPUTE_TILE(TT, Q, ER) do {                                                     \
        f32x4 a0_, a1_, a2_, a3_;                                                        \
        { const float v_ = -0.5f * (ER);                                                 \
          const f32x4 iv_ = {v_, v_, v_, v_};                                            \
          a0_ = iv_; a1_ = iv_; a2_ = iv_; a3_ = iv_; }                                  \
        const _Float16* Bq_ = (const _Float16*)(arena + (Q) * 32768);                    \
        const int cb_ = (colg * 16 + lm) * 256;                                          \
        _Pragma("unroll")                                                                \
        for (int ks = 0; ks < 8; ++ks) {                                                 \
            const int sw_ = ((ks * 4 + quad) ^ (lm & 7)) * 8;                            \
            const half8 bf_ = *(const half8*)(&Bq_[cb_ + sw_]);                          \
            a0_ = __builtin_amdgcn_mfma_f32_16x16x32_f16(af[0][ks], bf_, a0_, 0, 0, 0);  \
            a1_ = __builtin_amdgcn_mfma_f32_16x16x32_f16(af[1][ks], bf_, a1_, 0, 0, 0);  \
            a2_ = __builtin_amdgcn_mfma_f32_16x16x32_f16(af[2][ks], bf_, a2_, 0, 0, 0);  \
            a3_ = __builtin_amdgcn_mfma_f32_16x16x32_f16(af[3][ks], bf_, a3_, 0, 0, 0);  \
        }                                                                                \
        const unsigned kk_ = (unsigned)((TT) * TILE_CODES + colg * 16 + lm);             \
        _Pragma("unroll")                                                                \
        for (int r = 0; r < 4; ++r) {                                                    \
            { const float pv = __uint_as_float((__float_as_uint(a0_[r]) & 0xFFFFE000u) | kk_); \
              p2[r] = __builtin_amdgcn_fmed3f(p1[r], p2[r], pv); p1[r] = fmaxf(p1[r], pv); }   \
            { const float pv = __uint_as_float((__float_as_uint(a1_[r]) & 0xFFFFE000u) | kk_); \
              p2[4+r] = __builtin_amdgcn_fmed3f(p1[4+r], p2[4+r], pv); p1[4+r] = fmaxf(p1[4+r], pv); } \
            { const float pv = __uint_as_float((__float_as_uint(a2_[r]) & 0xFFFFE000u) | kk_); \
              p2[8+r] = __builtin_amdgcn_fmed3f(p1[8+r], p2[8+r], pv); p1[8+r] = fmaxf(p1[8+r], pv); } \
            { const float pv = __uint_as_float((__float_as_uint(a3_[r]) & 0xFFFFE000u) | kk_); \
              p2[12+r] = __builtin_amdgcn_fmed3f(p1[12+r], p2[12+r], pv); p1[12+r] = fmaxf(p1[12+r], pv); } \
        }                                                                                \
    } while (0)

    // issue tile 0 FIRST so its latency hides under the A-fragment load phase
    ISSUE_PKT(0, 0, e0);

    // ---- A fragments register-resident (fp32 x -> fp16): 64 rows -> 128 VGPRs ----
    half8 af[4][8];
#pragma unroll
    for (int am = 0; am < 4; ++am) {
        const float* xr = x + (size_t)(rowblk + am * 16 + lm) * DIM + quad * 8;
#pragma unroll
        for (int ks = 0; ks < 8; ++ks) {
            const float4 a = *(const float4*)(xr + ks * 32);
            const float4 b = *(const float4*)(xr + ks * 32 + 4);
            half8 h;
            h[0] = (_Float16)a.x; h[1] = (_Float16)a.y; h[2] = (_Float16)a.z; h[3] = (_Float16)a.w;
            h[4] = (_Float16)b.x; h[5] = (_Float16)b.y; h[6] = (_Float16)b.z; h[7] = (_Float16)b.w;
            af[am][ks] = h;
        }
    }

    // packed (score | index in low 13 mantissa bits) top-2 per row-slot (16 slots)
    float p1[16], p2[16];
#pragma unroll
    for (int i = 0; i < 16; ++i) { p1[i] = -INFINITY; p2[i] = -INFINITY; }

    // main loop: 1 tile per phase, 2 phases per iter (static buffer / e-reg names).
    // wait vmcnt(0) = packet issued one full tile earlier -> latency hidden.
    for (int T = 0; T < NT - 2; T += 2) {
        asm volatile("s_waitcnt vmcnt(0)" ::: "memory");
        __builtin_amdgcn_s_barrier();
        ISSUE_PKT(T + 1, 1, e1);
        COMPUTE_TILE(T, 0, e0);
        asm volatile("s_waitcnt vmcnt(0)" ::: "memory");
        __builtin_amdgcn_s_barrier();
        ISSUE_PKT(T + 2, 0, e0);
        COMPUTE_TILE(T + 1, 1, e1);
    }
    // peel: tiles 126, 127
    asm volatile("s_waitcnt vmcnt(0)" ::: "memory");
    __builtin_amdgcn_s_barrier();
    ISSUE_PKT(NT - 1, 1, e1);
    COMPUTE_TILE(NT - 2, 0, e0);
    asm volatile("s_waitcnt vmcnt(0)" ::: "memory");
    __builtin_amdgcn_s_barrier();
    COMPUTE_TILE(NT - 1, 1, e1);

    __syncthreads();   // full drain once; arena becomes merge scratch

    // ---- merge: per row, 64 streams x top-2 = 128 packed values -> top-4 ----
    // stride 129 floats: reader banks = (tid*129+p)%32 = (tid+p)%32 -> 2-way max
#pragma unroll
    for (int s = 0; s < 16; ++s) {
        const int row = (s >> 2) * 16 + quad * 4 + (s & 3);
        const int pos = (colg * 16 + lm) * 2;
        mb[row * 129 + pos] = p1[s];
        mb[row * 129 + pos + 1] = p2[s];
    }
    __syncthreads();
    if (tid < ROWS_PER_BLK) {
        float t1 = -INFINITY, t2 = -INFINITY, t3 = -INFINITY, t4 = -INFINITY;
        for (int p = 0; p < 128; ++p) {
            const float v = mb[tid * 129 + p];
            const float m1 = fminf(t1, v);
            t1 = fmaxf(t1, v);
            const float m2 = fminf(t2, m1);
            t2 = fmaxf(t2, m1);
            const float m3 = fminf(t3, m2);
            t3 = fmaxf(t3, m2);
            t4 = fmaxf(t4, m3);
        }
        top4s[tid][0] = t1; top4s[tid][1] = t2; top4s[tid][2] = t3; top4s[tid][3] = t4;
    }
    __syncthreads();

    // ---- exact fp32 recheck: 4 threads/row, 1 candidate each (256 thr = 64 rows) ----
    {
        const int row = tid >> 2;
        const int ci = tid & 3;
        const int k = (int)(__float_as_uint(top4s[row][ci]) & 8191u);
        const float4* x4 = (const float4*)(x + (size_t)(rowblk + row) * DIM);
        float cs[4];
#pragma unroll
        for (int co = 0; co < 4; ++co) {
            float s = 0.f;
            for (int c4 = 0; c4 < 16; ++c4) {
                const float4 v = x4[co * 16 + c4];
                s = fmaf(v.x, v.x, s); s = fmaf(v.y, v.y, s);
                s = fmaf(v.z, v.z, s); s = fmaf(v.w, v.w, s);
            }
            cs[co] = s;
        }
        const float xsq = ((cs[0] + cs[1]) + cs[2]) + cs[3];
        const float4* e4 = (const float4*)(embed + (size_t)k * DIM);
        float dot = 0.f, es = 0.f;
        for (int c4 = 0; c4 < 64; ++c4) {
            const float4 xv = x4[c4], evv = e4[c4];
            dot = fmaf(xv.x, evv.x, dot); dot = fmaf(xv.y, evv.y, dot);
            dot = fmaf(xv.z, evv.z, dot); dot = fmaf(xv.w, evv.w, dot);
            es = fmaf(evv.x, evv.x, es); es = fmaf(evv.y, evv.y, es);
            es = fmaf(evv.z, evv.z, es); es = fmaf(evv.w, evv.w, es);
        }
        rd[row][ci] = fmaf(-2.0f, dot, xsq) + es;   // validated rounding sequence
        rk[row][ci] = k;
    }
    __syncthreads();
    if (tid < ROWS_PER_BLK) {
        float best = rd[tid][0]; int bidx = rk[tid][0];
#pragma unroll
        for (int t = 1; t < 4; ++t) {
            const float d2 = rd[tid][t]; const int k2 = rk[tid][t];
            if (d2 < best || (d2 == best && k2 < bidx)) { best = d2; bidx = k2; }
        }
        win[tid] = bidx;
    }
    __syncthreads();

    // ---- coalesced gather (256 threads: 4 row-banks x 16 rows) ----
    {
        const int q = tid & 63;
        const int rb = tid >> 6;   // 0..3
        const float4* e4 = (const float4*)embed;
        float4* o4 = (float4*)out;
#pragma unroll
        for (int p = 0; p < 16; ++p) {
            const int r = rb + p * 4;
            const int k = win[r];
            o4[(size_t)(rowblk + r) * 64 + q] = e4[(size_t)k * 64 + q];
        }
    }
#undef COMPUTE_TILE
#undef ISSUE_PKT
}

// ---------------- Fallback (round-1 kernel, passed absmax 0) ----------------
#define BM 64
#define BN 128
#define BC 64
#define NKT (KCODES / BN)
#define NCC (DIM / BC)

__global__ __launch_bounds__(256, 3) void vq_argmin_gather(
    const float* __restrict__ x, const float* __restrict__ embed,
    float* __restrict__ out)
{
    __shared__ __align__(16) float xs[BC * BM];
    __shared__ __align__(16) float es[BC * BN];
    const int tid = threadIdx.x;
    const int tx = tid & 15;
    const int ty = tid >> 4;
    const int row0 = blockIdx.x * BM;
    float xsq[4];
    {
        const int m = tid >> 2;
        const int quarter = tid & 3;
        const float* xr = x + (size_t)(row0 + m) * DIM + quarter * 64;
        float s = 0.f;
        for (int c = 0; c < 64; ++c) s = fmaf(xr[c], xr[c], s);
        es[tid] = s;
        __syncthreads();
#pragma unroll
        for (int i = 0; i < 4; ++i) {
            const int r = 4 * ty + i;
            xsq[i] = ((es[4*r] + es[4*r+1]) + es[4*r+2]) + es[4*r+3];
        }
        __syncthreads();
    }
    float bd[4] = {INFINITY, INFINITY, INFINITY, INFINITY};
    int bk[4] = {0, 0, 0, 0};
    for (int kt = 0; kt < NKT; ++kt) {
        const int k0 = kt * BN;
        float acc[4][8];
#pragma unroll
        for (int i = 0; i < 4; ++i)
#pragma unroll
            for (int j = 0; j < 8; ++j) acc[i][j] = 0.f;
        float e_acc = 0.f;
        for (int cc = 0; cc < NCC; ++cc) {
            __syncthreads();
            {
                const int q = tid & 15;
                const int nb = tid >> 4;
#pragma unroll
                for (int p = 0; p < 4; ++p) {
                    const int m = nb + 16 * p;
                    const float4 v = *(const float4*)(x + (size_t)(row0 + m) * DIM + cc * BC + 4 * q);
                    xs[(4*q+0)*BM+m] = v.x; xs[(4*q+1)*BM+m] = v.y;
                    xs[(4*q+2)*BM+m] = v.z; xs[(4*q+3)*BM+m] = v.w;
                }
#pragma unroll
                for (int p = 0; p < 8; ++p) {
                    const int n = nb + 16 * p;
                    const float4 v = *(const float4*)(embed + (size_t)(k0 + n) * DIM + cc * BC + 4 * q);
                    es[(4*q+0)*BN+n] = v.x; es[(4*q+1)*BN+n] = v.y;
                    es[(4*q+2)*BN+n] = v.z; es[(4*q+3)*BN+n] = v.w;
                }
            }
            __syncthreads();
            if (tid < BN) {
#pragma unroll 8
                for (int c = 0; c < BC; ++c) { const float v = es[c*BN+tid]; e_acc = fmaf(v, v, e_acc); }
            }
#pragma unroll 8
            for (int c = 0; c < BC; ++c) {
                const float4 a0 = *(const float4*)&xs[c*BM+4*ty];
                const float4 b0 = *(const float4*)&es[c*BN+4*tx];
                const float4 b1 = *(const float4*)&es[c*BN+64+4*tx];
                const float a[4] = {a0.x, a0.y, a0.z, a0.w};
                const float b[8] = {b0.x, b0.y, b0.z, b0.w, b1.x, b1.y, b1.z, b1.w};
#pragma unroll
                for (int i = 0; i < 4; ++i)
#pragma unroll
                    for (int j = 0; j < 8; ++j) acc[i][j] = fmaf(a[i], b[j], acc[i][j]);
            }
        }
        __syncthreads();
        if (tid < BN) es[tid] = e_acc;
        __syncthreads();
        float esq2[8];
#pragma unroll
        for (int j = 0; j < 4; ++j) { esq2[j] = es[4*tx+j]; esq2[4+j] = es[64+4*tx+j]; }
#pragma unroll
        for (int i = 0; i < 4; ++i)
#pragma unroll
            for (int j = 0; j < 8; ++j) {
                const float d = fmaf(-2.0f, acc[i][j], xsq[i]) + esq2[j];
                const int kk = k0 + ((j < 4) ? (4*tx+j) : (64+4*tx+(j-4)));
                if (d < bd[i]) { bd[i] = d; bk[i] = kk; }
            }
    }
    __syncthreads();
    float* red_d = xs;
    int* red_k = (int*)es;
#pragma unroll
    for (int i = 0; i < 4; ++i) { const int r = 4*ty+i; red_d[r*16+tx] = bd[i]; red_k[r*16+tx] = bk[i]; }
    __syncthreads();
    int winner = 0;
    if (tid < BM) {
        float best = red_d[tid*16]; int bidx = red_k[tid*16];
#pragma unroll
        for (int t = 1; t < 16; ++t) {
            const float d2 = red_d[tid*16+t]; const int k2 = red_k[tid*16+t];
            if (d2 < best || (d2 == best && k2 < bidx)) { best = d2; bidx = k2; }
        }
        winner = bidx;
    }
    __syncthreads();
    int* wn = (int*)xs;
    if (tid < BM) wn[tid] = winner;
    __syncthreads();
    {
        const int q = tid & 63;
        const int rb = tid >> 6;
        const float4* e4 = (const float4*)embed;
        float4* o4 = (float4*)out;
#pragma unroll
        for (int p = 0; p < 16; ++p) {
            const int rr = rb + 4 * p;
            const int k = wn[rr];
            o4[(size_t)(row0 + rr) * 64 + q] = e4[(size_t)k * 64 + q];
        }
    }
}

extern "C" void kernel_launch(void* const* d_in, const int* in_sizes, int n_in,
                              void* d_out, int out_size, void* d_ws, size_t ws_size,
                              hipStream_t stream) {
    const float* x = (const float*)d_in[0];
    const float* embed = (const float*)d_in[1];
    float* out = (float*)d_out;

    if (ws_size < (size_t)WS_NEED) {
        hipLaunchKernelGGL(vq_argmin_gather, dim3(NROWS / BM), dim3(256), 0, stream, x, embed, out);
        return;
    }
    char* ws = (char*)d_ws;
    _Float16* Es = (_Float16*)(ws + ES_OFF);
    float* esq = (float*)(ws + ESQ_OFF);

    hipLaunchKernelGGL(cvt_esq, dim3(128), dim3(256), 0, stream, embed, Es, esq);
    hipLaunchKernelGGL(vq_fused, dim3(NROWS / ROWS_PER_BLK), dim3(256), 0, stream, x, Es, esq, embed, out);
}

// Round 10
// 258.066 us; speedup vs baseline: 1.5444x; 1.5444x over previous
//
#include <hip/hip_runtime.h>
#include <math.h>

// EuclideanCodebook: x (8,4096,256) fp32, embed (8192,256) fp32
// out = embed[argmin_k ||x - e_k||^2], first-index tie rule.
//
// R15: R11 shell (the only viable config per the R6-R14 ledger: 1 WG/CU
// always; VGPR cap = 65536/threads; => 512 thr, 2 waves/SIMD, 128 regs,
// 4rowg x 2colg dup-4) + latency-diet:
//  - esq staged to LDS via global_load_lds size=4 (wave 0, 1/tile): frees
//    8 e-VGPRs, removes per-tile esq VMEM from the wait path. R14's clean
//    WRITE_SIZE revealed all 512-thr variants spill ~25MB (demand ~170 at
//    cap 128, prologue spike + zero loop slack) -> every reg counts.
//  - inner loop addressing = R9b's validated E/O byte-base decomposition
//    (addr(ks) = (ks&1?pO:pE) + ks*64), stream 1 = +8192 imm -> ds_read
//    with immediate offsets only, zero VALU in the MFMA loop.
//  - R12's proven sync (absmax 0): phase = 2 tiles, wait vmcnt(0) (packet
//    issued one full phase earlier -> free) + raw s_barrier, issue-after-
//    barrier into the pair read last phase (WAR-safe). 64 barriers.
//  - cvt_esq grid 128->256 blocks (was on half the CUs).
// Selection arithmetic bit-identical to R11 (absmax 0): f16 MFMA approx,
// packed (score|idx) med3 top-2, 32 streams x top-2 -> top-4, exact fp32
// recheck (validated rounding), coalesced gather.

#define DIM 256
#define KCODES 8192
#define NROWS 32768
#define TILE_CODES 64
#define NT (KCODES / TILE_CODES)   // 128

typedef _Float16 half8 __attribute__((ext_vector_type(8)));
typedef _Float16 half4_t __attribute__((ext_vector_type(4)));
typedef float f32x4 __attribute__((ext_vector_type(4)));

// ---- ws layout (bytes) ----
#define ES_OFF 0u                 // 8192*256 f16 = 4194304
#define ESQ_OFF 4194304u          // 8192 f32     = 32768
#define WS_NEED 4227072u

#define GLOAD_LDS16(gp, lp) \
    __builtin_amdgcn_global_load_lds((const __attribute__((address_space(1))) void*)(gp), \
                                     (__attribute__((address_space(3))) void*)(lp), 16, 0, 0)
#define GLOAD_LDS4(gp, lp) \
    __builtin_amdgcn_global_load_lds((const __attribute__((address_space(1))) void*)(gp), \
                                     (__attribute__((address_space(3))) void*)(lp), 4, 0, 0)

// ---------------- prep: embed fp32 -> fp16 + e_sq (approx use only) ----------------
// 256 blocks x 256 thr; 8 lanes per code, 32 floats each.
__global__ void cvt_esq(const float* __restrict__ emb, _Float16* __restrict__ Es,
                        float* __restrict__ esq) {
    const int gid = blockIdx.x * 256 + threadIdx.x;
    const int code = gid >> 3, oct = gid & 7;
    const float4* src = (const float4*)(emb + (size_t)code * DIM + oct * 32);
    half4_t* dst = (half4_t*)(Es + (size_t)code * DIM + oct * 32);
    float s = 0.f;
#pragma unroll
    for (int i = 0; i < 8; ++i) {
        const float4 v = src[i];
        half4_t h;
        h[0] = (_Float16)v.x; h[1] = (_Float16)v.y; h[2] = (_Float16)v.z; h[3] = (_Float16)v.w;
        dst[i] = h;
        s = fmaf(v.x, v.x, s); s = fmaf(v.y, v.y, s);
        s = fmaf(v.z, v.z, s); s = fmaf(v.w, v.w, s);
    }
    s += __shfl_xor(s, 1);
    s += __shfl_xor(s, 2);
    s += __shfl_xor(s, 4);
    if (oct == 0) esq[code] = s;
}

// ---------------- fused: MFMA score + top-4 + exact recheck + gather ----------------
// grid 256 blocks x 512 threads (8 waves). Block owns rows [blockIdx*128, +128).
// Wave wv: rowg = wv&3 (32-row slice), colg = wv>>2 (32-col slice of 64-code tile).
__global__ __attribute__((amdgpu_flat_work_group_size(512, 512)))
__attribute__((amdgpu_waves_per_eu(1, 2))) void vq_fused(
    const float* __restrict__ x, const _Float16* __restrict__ Es,
    const float* __restrict__ esq, const float* __restrict__ embed,
    float* __restrict__ out)
{
    __shared__ __align__(16) char arena[132096];   // 4x32KB tile bufs + 4x256B esq + overlays

    const int tid = threadIdx.x;
    const int lane = tid & 63;
    const int wv = tid >> 6;        // 0..7
    const int rowg = wv & 3;        // 4 row groups x 32 rows
    const int colg = wv >> 2;       // 2 col groups x 32 cols
    const int lm = lane & 15;
    const int quad = lane >> 4;
    const int rowblk = blockIdx.x * 128;

    float* esql = (float*)(arena + 131072);             // 4 x 64 f32 esq slots

    // post-K-loop overlays inside the arena (all uses after the post-loop barrier)
    float* mb = (float*)arena;                          // [128][65] f = 33280 B
    float (*top4s)[4] = (float (*)[4])(arena + 34816);  // 2048 B
    float (*rd)[4] = (float (*)[4])(arena + 36864);     // 2048 B
    int (*rk)[4] = (int (*)[4])(arena + 38912);         // 2048 B
    int* win = (int*)(arena + 40960);                   // 512 B

    // ---- per-lane LDS read bases (R9b-validated E/O decomposition):
    // byte addr(ks) = (ks&1 ? pO : pE) + ks*64 ; stream1 = +8192 immediate.
    const int z = lm & 7;
    const int cl0 = colg * 32 + lm;
    const int base_b = cl0 * 512 + (quad ^ (z & 3)) * 16;
    const int zb64 = (z >> 2) * 64;
    const char* pE0 = arena + base_b + zb64;
    const char* pO0 = arena + base_b - zb64;

    // staging role: wave stages codes [wv*8, wv*8+8) of each tile (4 x 1KB loads)
    const int bpos = lane & 31;
    const int cl_lo = wv * 8 + (lane >> 5);
    const _Float16* g0 = Es + (size_t)(cl_lo + 0) * 256 + (size_t)((bpos ^ ((cl_lo + 0) & 7)) * 8);
    const _Float16* g1 = Es + (size_t)(cl_lo + 2) * 256 + (size_t)((bpos ^ ((cl_lo + 2) & 7)) * 8);
    const _Float16* g2 = Es + (size_t)(cl_lo + 4) * 256 + (size_t)((bpos ^ ((cl_lo + 4) & 7)) * 8);
    const _Float16* g3 = Es + (size_t)(cl_lo + 6) * 256 + (size_t)((bpos ^ ((cl_lo + 6) & 7)) * 8);
    const float* esq_lane = esq + lane;

    // packet = PAIR of tiles 2TP,2TP+1 -> bufs BB,BB+1 (+ esq slots BB,BB+1)
#define ISSUE_PAIR(TP, BB) do {                                               \
        char* d0_ = arena + (BB) * 32768;                                     \
        GLOAD_LDS16(g0, d0_ + (wv * 8 + 0) * 512);                            \
        GLOAD_LDS16(g1, d0_ + (wv * 8 + 2) * 512);                            \
        GLOAD_LDS16(g2, d0_ + (wv * 8 + 4) * 512);                            \
        GLOAD_LDS16(g3, d0_ + (wv * 8 + 6) * 512);                            \
        g0 += TILE_CODES * 256; g1 += TILE_CODES * 256;                       \
        g2 += TILE_CODES * 256; g3 += TILE_CODES * 256;                       \
        char* d1_ = arena + ((BB) + 1) * 32768;                               \
        GLOAD_LDS16(g0, d1_ + (wv * 8 + 0) * 512);                            \
        GLOAD_LDS16(g1, d1_ + (wv * 8 + 2) * 512);                            \
        GLOAD_LDS16(g2, d1_ + (wv * 8 + 4) * 512);                            \
        GLOAD_LDS16(g3, d1_ + (wv * 8 + 6) * 512);                            \
        g0 += TILE_CODES * 256; g1 += TILE_CODES * 256;                       \
        g2 += TILE_CODES * 256; g3 += TILE_CODES * 256;                       \
        if (wv == 0) {                                                        \
            GLOAD_LDS4(esq_lane + (size_t)(2 * (TP)) * 64, esql + (BB) * 64); \
            GLOAD_LDS4(esq_lane + (size_t)(2 * (TP) + 1) * 64, esql + ((BB) + 1) * 64); \
        }                                                                     \
    } while (0)

    // one tile: 16 ds_read_b128 (imm offsets only), 32 MFMA, 32-value top-2
#define COMPUTE_TILE(TT, Q) do {                                                         \
        const float e0_ = esql[(Q) * 64 + colg * 32 + lm];                               \
        const float e1_ = esql[(Q) * 64 + colg * 32 + 16 + lm];                          \
        f32x4 acc00, acc01, acc10, acc11;                                                \
        { const float v0_ = -0.5f * e0_, v1_ = -0.5f * e1_;                              \
          const f32x4 i0_ = {v0_, v0_, v0_, v0_};                                        \
          const f32x4 i1_ = {v1_, v1_, v1_, v1_};                                        \
          acc00 = i0_; acc10 = i0_; acc01 = i1_; acc11 = i1_; }                          \
        const char* pE_ = pE0 + (Q) * 32768;                                             \
        const char* pO_ = pO0 + (Q) * 32768;                                             \
        _Pragma("unroll")                                                                \
        for (int ks = 0; ks < 8; ++ks) {                                                 \
            const char* pb_ = (ks & 1) ? pO_ : pE_;                                      \
            const half8 bf0_ = *(const half8*)(pb_ + ks * 64);                           \
            const half8 bf1_ = *(const half8*)(pb_ + ks * 64 + 8192);                    \
            acc00 = __builtin_amdgcn_mfma_f32_16x16x32_f16(af[0][ks], bf0_, acc00, 0, 0, 0); \
            acc01 = __builtin_amdgcn_mfma_f32_16x16x32_f16(af[0][ks], bf1_, acc01, 0, 0, 0); \
            acc10 = __builtin_amdgcn_mfma_f32_16x16x32_f16(af[1][ks], bf0_, acc10, 0, 0, 0); \
            acc11 = __builtin_amdgcn_mfma_f32_16x16x32_f16(af[1][ks], bf1_, acc11, 0, 0, 0); \
        }                                                                                \
        const unsigned kk0_ = (unsigned)((TT) * TILE_CODES + colg * 32 + lm);            \
        const unsigned kk1_ = kk0_ + 16u;                                                \
        _Pragma("unroll")                                                                \
        for (int r = 0; r < 4; ++r) {                                                    \
            { const float pv = __uint_as_float((__float_as_uint(acc00[r]) & 0xFFFFE000u) | kk0_); \
              p2[r] = __builtin_amdgcn_fmed3f(p1[r], p2[r], pv); p1[r] = fmaxf(p1[r], pv); }      \
            { const float pv = __uint_as_float((__float_as_uint(acc01[r]) & 0xFFFFE000u) | kk1_); \
              p2[r] = __builtin_amdgcn_fmed3f(p1[r], p2[r], pv); p1[r] = fmaxf(p1[r], pv); }      \
            { const float pv = __uint_as_float((__float_as_uint(acc10[r]) & 0xFFFFE000u) | kk0_); \
              p2[4+r] = __builtin_amdgcn_fmed3f(p1[4+r], p2[4+r], pv); p1[4+r] = fmaxf(p1[4+r], pv); } \
            { const float pv = __uint_as_float((__float_as_uint(acc11[r]) & 0xFFFFE000u) | kk1_); \
              p2[4+r] = __builtin_amdgcn_fmed3f(p1[4+r], p2[4+r], pv); p1[4+r] = fmaxf(p1[4+r], pv); } \
        }                                                                                \
    } while (0)

    // issue pair 0 FIRST so its latency hides under the A-fragment load phase
    ISSUE_PAIR(0, 0);

    // ---- A fragments register-resident (fp32 x -> fp16): 32 rows -> 64 VGPRs ----
    half8 af[2][8];
#pragma unroll
    for (int am = 0; am < 2; ++am) {
        const float* xr = x + (size_t)(rowblk + rowg * 32 + am * 16 + lm) * DIM + quad * 8;
#pragma unroll
        for (int ks = 0; ks < 8; ++ks) {
            const float4 a = *(const float4*)(xr + ks * 32);
            const float4 b = *(const float4*)(xr + ks * 32 + 4);
            half8 h;
            h[0] = (_Float16)a.x; h[1] = (_Float16)a.y; h[2] = (_Float16)a.z; h[3] = (_Float16)a.w;
            h[4] = (_Float16)b.x; h[5] = (_Float16)b.y; h[6] = (_Float16)b.z; h[7] = (_Float16)b.w;
            af[am][ks] = h;
        }
    }

    // packed (score | index in low 13 mantissa bits) top-2 per row-slot (8 slots)
    float p1[8], p2[8];
#pragma unroll
    for (int i = 0; i < 8; ++i) { p1[i] = -INFINITY; p2[i] = -INFINITY; }

    // main loop: phase = 2 tiles; wait vmcnt(0) (packet issued one full phase
    // earlier -> free), raw barrier, issue next pair into the pair read last
    // phase (WAR-safe), compute current pair. 64 phases total.
    for (int k = 0; k < 62; k += 2) {
        asm volatile("s_waitcnt vmcnt(0)" ::: "memory");
        __builtin_amdgcn_s_barrier();
        ISSUE_PAIR(k + 1, 2);
        COMPUTE_TILE(2 * k + 0, 0);
        COMPUTE_TILE(2 * k + 1, 1);
        asm volatile("s_waitcnt vmcnt(0)" ::: "memory");
        __builtin_amdgcn_s_barrier();
        ISSUE_PAIR(k + 2, 0);
        COMPUTE_TILE(2 * k + 2, 2);
        COMPUTE_TILE(2 * k + 3, 3);
    }
    // peel: pairs 62, 63
    asm volatile("s_waitcnt vmcnt(0)" ::: "memory");
    __builtin_amdgcn_s_barrier();
    ISSUE_PAIR(63, 2);
    COMPUTE_TILE(124, 0);
    COMPUTE_TILE(125, 1);
    asm volatile("s_waitcnt vmcnt(0)" ::: "memory");
    __builtin_amdgcn_s_barrier();
    COMPUTE_TILE(126, 2);
    COMPUTE_TILE(127, 3);

    __syncthreads();   // full drain once; arena becomes merge scratch

    // ---- merge: per row, 32 streams x top-2 = 64 packed values -> top-4 ----
    // stride 65 floats: reader banks = (tid*65+p)%32 = (tid+p)%32 -> conflict-free
#pragma unroll
    for (int s = 0; s < 8; ++s) {
        const int row = rowg * 32 + (s >> 2) * 16 + quad * 4 + (s & 3);
        const int pos = (colg * 16 + lm) * 2;
        mb[row * 65 + pos] = p1[s];
        mb[row * 65 + pos + 1] = p2[s];
    }
    __syncthreads();
    if (tid < 128) {
        float t1 = -INFINITY, t2 = -INFINITY, t3 = -INFINITY, t4 = -INFINITY;
        for (int p = 0; p < 64; ++p) {
            const float v = mb[tid * 65 + p];
            const float m1 = fminf(t1, v);
            t1 = fmaxf(t1, v);
            const float m2 = fminf(t2, m1);
            t2 = fmaxf(t2, m1);
            const float m3 = fminf(t3, m2);
            t3 = fmaxf(t3, m2);
            t4 = fmaxf(t4, m3);
        }
        top4s[tid][0] = t1; top4s[tid][1] = t2; top4s[tid][2] = t3; top4s[tid][3] = t4;
    }
    __syncthreads();

    // ---- exact fp32 recheck: 4 threads/row, 1 candidate each ----
    {
        const int row = tid >> 2;
        const int ci = tid & 3;
        const int k = (int)(__float_as_uint(top4s[row][ci]) & 8191u);
        const float4* x4 = (const float4*)(x + (size_t)(rowblk + row) * DIM);
        float cs[4];
#pragma unroll
        for (int co = 0; co < 4; ++co) {
            float s = 0.f;
            for (int c4 = 0; c4 < 16; ++c4) {
                const float4 v = x4[co * 16 + c4];
                s = fmaf(v.x, v.x, s); s = fmaf(v.y, v.y, s);
                s = fmaf(v.z, v.z, s); s = fmaf(v.w, v.w, s);
            }
            cs[co] = s;
        }
        const float xsq = ((cs[0] + cs[1]) + cs[2]) + cs[3];
        const float4* e4 = (const float4*)(embed + (size_t)k * DIM);
        float dot = 0.f, es = 0.f;
        for (int c4 = 0; c4 < 64; ++c4) {
            const float4 xv = x4[c4], evv = e4[c4];
            dot = fmaf(xv.x, evv.x, dot); dot = fmaf(xv.y, evv.y, dot);
            dot = fmaf(xv.z, evv.z, dot); dot = fmaf(xv.w, evv.w, dot);
            es = fmaf(evv.x, evv.x, es); es = fmaf(evv.y, evv.y, es);
            es = fmaf(evv.z, evv.z, es); es = fmaf(evv.w, evv.w, es);
        }
        rd[row][ci] = fmaf(-2.0f, dot, xsq) + es;   // validated rounding sequence
        rk[row][ci] = k;
    }
    __syncthreads();
    if (tid < 128) {
        float best = rd[tid][0]; int bidx = rk[tid][0];
#pragma unroll
        for (int t = 1; t < 4; ++t) {
            const float d2 = rd[tid][t]; const int k2 = rk[tid][t];
            if (d2 < best || (d2 == best && k2 < bidx)) { best = d2; bidx = k2; }
        }
        win[tid] = bidx;
    }
    __syncthreads();

    // ---- coalesced gather ----
    {
        const int q = tid & 63;
        const int rb = tid >> 6;
        const float4* e4 = (const float4*)embed;
        float4* o4 = (float4*)out;
#pragma unroll
        for (int p = 0; p < 16; ++p) {
            const int r = rb + p * 8;
            const int k = win[r];
            o4[(size_t)(rowblk + r) * 64 + q] = e4[(size_t)k * 64 + q];
        }
    }
#undef COMPUTE_TILE
#undef ISSUE_PAIR
}

// ---------------- Fallback (round-1 kernel, passed absmax 0) ----------------
#define BM 64
#define BN 128
#define BC 64
#define NKT (KCODES / BN)
#define NCC (DIM / BC)

__global__ __launch_bounds__(256, 3) void vq_argmin_gather(
    const float* __restrict__ x, const float* __restrict__ embed,
    float* __restrict__ out)
{
    __shared__ __align__(16) float xs[BC * BM];
    __shared__ __align__(16) float es[BC * BN];
    const int tid = threadIdx.x;
    const int tx = tid & 15;
    const int ty = tid >> 4;
    const int row0 = blockIdx.x * BM;
    float xsq[4];
    {
        const int m = tid >> 2;
        const int quarter = tid & 3;
        const float* xr = x + (size_t)(row0 + m) * DIM + quarter * 64;
        float s = 0.f;
        for (int c = 0; c < 64; ++c) s = fmaf(xr[c], xr[c], s);
        es[tid] = s;
        __syncthreads();
#pragma unroll
        for (int i = 0; i < 4; ++i) {
            const int r = 4 * ty + i;
            xsq[i] = ((es[4*r] + es[4*r+1]) + es[4*r+2]) + es[4*r+3];
        }
        __syncthreads();
    }
    float bd[4] = {INFINITY, INFINITY, INFINITY, INFINITY};
    int bk[4] = {0, 0, 0, 0};
    for (int kt = 0; kt < NKT; ++kt) {
        const int k0 = kt * BN;
        float acc[4][8];
#pragma unroll
        for (int i = 0; i < 4; ++i)
#pragma unroll
            for (int j = 0; j < 8; ++j) acc[i][j] = 0.f;
        float e_acc = 0.f;
        for (int cc = 0; cc < NCC; ++cc) {
            __syncthreads();
            {
                const int q = tid & 15;
                const int nb = tid >> 4;
#pragma unroll
                for (int p = 0; p < 4; ++p) {
                    const int m = nb + 16 * p;
                    const float4 v = *(const float4*)(x + (size_t)(row0 + m) * DIM + cc * BC + 4 * q);
                    xs[(4*q+0)*BM+m] = v.x; xs[(4*q+1)*BM+m] = v.y;
                    xs[(4*q+2)*BM+m] = v.z; xs[(4*q+3)*BM+m] = v.w;
                }
#pragma unroll
                for (int p = 0; p < 8; ++p) {
                    const int n = nb + 16 * p;
                    const float4 v = *(const float4*)(embed + (size_t)(k0 + n) * DIM + cc * BC + 4 * q);
                    es[(4*q+0)*BN+n] = v.x; es[(4*q+1)*BN+n] = v.y;
                    es[(4*q+2)*BN+n] = v.z; es[(4*q+3)*BN+n] = v.w;
                }
            }
            __syncthreads();
            if (tid < BN) {
#pragma unroll 8
                for (int c = 0; c < BC; ++c) { const float v = es[c*BN+tid]; e_acc = fmaf(v, v, e_acc); }
            }
#pragma unroll 8
            for (int c = 0; c < BC; ++c) {
                const float4 a0 = *(const float4*)&xs[c*BM+4*ty];
                const float4 b0 = *(const float4*)&es[c*BN+4*tx];
                const float4 b1 = *(const float4*)&es[c*BN+64+4*tx];
                const float a[4] = {a0.x, a0.y, a0.z, a0.w};
                const float b[8] = {b0.x, b0.y, b0.z, b0.w, b1.x, b1.y, b1.z, b1.w};
#pragma unroll
                for (int i = 0; i < 4; ++i)
#pragma unroll
                    for (int j = 0; j < 8; ++j) acc[i][j] = fmaf(a[i], b[j], acc[i][j]);
            }
        }
        __syncthreads();
        if (tid < BN) es[tid] = e_acc;
        __syncthreads();
        float esq2[8];
#pragma unroll
        for (int j = 0; j < 4; ++j) { esq2[j] = es[4*tx+j]; esq2[4+j] = es[64+4*tx+j]; }
#pragma unroll
        for (int i = 0; i < 4; ++i)
#pragma unroll
            for (int j = 0; j < 8; ++j) {
                const float d = fmaf(-2.0f, acc[i][j], xsq[i]) + esq2[j];
                const int kk = k0 + ((j < 4) ? (4*tx+j) : (64+4*tx+(j-4)));
                if (d < bd[i]) { bd[i] = d; bk[i] = kk; }
            }
    }
    __syncthreads();
    float* red_d = xs;
    int* red_k = (int*)es;
#pragma unroll
    for (int i = 0; i < 4; ++i) { const int r = 4*ty+i; red_d[r*16+tx] = bd[i]; red_k[r*16+tx] = bk[i]; }
    __syncthreads();
    int winner = 0;
    if (tid < BM) {
        float best = red_d[tid*16]; int bidx = red_k[tid*16];
#pragma unroll
        for (int t = 1; t < 16; ++t) {
            const float d2 = red_d[tid*16+t]; const int k2 = red_k[tid*16+t];
            if (d2 < best || (d2 == best && k2 < bidx)) { best = d2; bidx = k2; }
        }
        winner = bidx;
    }
    __syncthreads();
    int* wn = (int*)xs;
    if (tid < BM) wn[tid] = winner;
    __syncthreads();
    {
        const int q = tid & 63;
        const int rb = tid >> 6;
        const float4* e4 = (const float4*)embed;
        float4* o4 = (float4*)out;
#pragma unroll
        for (int p = 0; p < 16; ++p) {
            const int rr = rb + 4 * p;
            const int k = wn[rr];
            o4[(size_t)(row0 + rr) * 64 + q] = e4[(size_t)k * 64 + q];
        }
    }
}

extern "C" void kernel_launch(void* const* d_in, const int* in_sizes, int n_in,
                              void* d_out, int out_size, void* d_ws, size_t ws_size,
                              hipStream_t stream) {
    const float* x = (const float*)d_in[0];
    const float* embed = (const float*)d_in[1];
    float* out = (float*)d_out;

    if (ws_size < (size_t)WS_NEED) {
        hipLaunchKernelGGL(vq_argmin_gather, dim3(NROWS / BM), dim3(256), 0, stream, x, embed, out);
        return;
    }
    char* ws = (char*)d_ws;
    _Float16* Es = (_Float16*)(ws + ES_OFF);
    float* esq = (float*)(ws + ESQ_OFF);

    hipLaunchKernelGGL(cvt_esq, dim3(256), dim3(256), 0, stream, embed, Es, esq);
    hipLaunchKernelGGL(vq_fused, dim3(256), dim3(512), 0, stream, x, Es, esq, embed, out);
}